// Round 4
// baseline (702.347 us; speedup 1.0000x reference)
//
#include <hip/hip_runtime.h>
#include <math.h>

// SimilarityTreeLSTM on MI355X — round 6: tree grid-barrier (16x16 fan-in,
// padded lines, replicated release flags) + stage overlap + root fold.
//
// Round-5 post-mortem: removing per-barrier wbl2/inv saved only ~6us/barrier;
// ~28us/barrier persists with near-zero utilization. Surviving hypothesis:
// same-address contention — 256 fetch_adds + 255 pollers on ONE counter line
// serialize at the L3 coherence point. This round:
//   * tree barrier: 16 leaf counters (one 64B line each, 16 blocks/group),
//     last-of-group bumps root, last-at-root writes 16 replicated release
//     flags; each block polls only its group's flag (16 pollers/line).
//   * stages: S1 = WxT transpose + zero rows -> bar; S2 = prege GEMM
//     OVERLAPPED with WiouhT/WfhT/Whb prep -> bar; C0 leaf gate -> bar;
//     4 phases (d4,d3,d2,d1) gemm->bar->gate->bar; root gemm + gating +
//     head fully in block 0 (wave-sliced, __syncthreads only). 11 barriers.
//   * #pragma unroll 2 on gemm K-loops (relaxed-atomic loads don't pipeline
//     across iterations), unroll 4 on head GEMV.
// Coherence model unchanged from round 5: mutable cross-block tensors via
// relaxed AGENT-scope atomics (sc0 sc1, L3 coherence point); write-once
// tensors written coherently, read cached.
//
// Level decomposition (deterministic from _build_children(512,4), j = 511-i):
//   leaves [0,171) | d4 [171,427) | d3 [427,491) | d2 [491,507)
//   | d1 [507,511) | root [511,512)
// Pad child index 512 maps to a per-tree zero row ([2][513][512] state bufs).
//
// MFMA: v_mfma_f32_16x16x32_bf16. A-frag: lane holds A[m=lane&15][k=q*8+j],
// B-frag: B[k=q*8+j][n=lane&15] (W stored transposed -> 16B contiguous load),
// C/D: col=lane&15, row=q*4+reg.  [per guide §3, verified]

typedef __attribute__((ext_vector_type(8))) __bf16 bf16x8;
typedef __attribute__((ext_vector_type(4))) float f32x4;
typedef unsigned long long u64;

#define GRID 256
#define NBAR 12
#define READY_MAGIC 0x13579BDFu

__device__ __forceinline__ float sigm(float x) { return 1.0f / (1.0f + __expf(-x)); }

__device__ __forceinline__ unsigned short f2bf(float f) {
    union { float f; unsigned int u; } v; v.f = f;
    unsigned int r = v.u + 0x7FFF + ((v.u >> 16) & 1);
    return (unsigned short)(r >> 16);
}
__device__ __forceinline__ float bf2f(unsigned short b) {
    union { unsigned int u; float f; } v; v.u = ((unsigned int)b) << 16;
    return v.f;
}
__device__ __forceinline__ f32x4 mfma16(bf16x8 a, bf16x8 b, f32x4 c) {
    return __builtin_amdgcn_mfma_f32_16x16x32_bf16(a, b, c, 0, 0, 0);
}
__device__ __forceinline__ bf16x8 load_f32_as_bf8(const float* p) {
    float4 x = *(const float4*)p;
    float4 y = *(const float4*)(p + 4);
    bf16x8 r;
    r[0] = (__bf16)x.x; r[1] = (__bf16)x.y; r[2] = (__bf16)x.z; r[3] = (__bf16)x.w;
    r[4] = (__bf16)y.x; r[5] = (__bf16)y.y; r[6] = (__bf16)y.z; r[7] = (__bf16)y.w;
    return r;
}

// ---- coherent (agent-scope, relaxed) access helpers -----------------------
__device__ __forceinline__ u64 ald8(const void* p) {
    return __hip_atomic_load((u64*)p, __ATOMIC_RELAXED, __HIP_MEMORY_SCOPE_AGENT);
}
__device__ __forceinline__ void ast8(void* p, u64 v) {
    __hip_atomic_store((u64*)p, v, __ATOMIC_RELAXED, __HIP_MEMORY_SCOPE_AGENT);
}
__device__ __forceinline__ void ast4u(void* p, unsigned v) {
    __hip_atomic_store((unsigned*)p, v, __ATOMIC_RELAXED, __HIP_MEMORY_SCOPE_AGENT);
}
__device__ __forceinline__ unsigned ald4(const void* p) {
    return __hip_atomic_load((unsigned*)p, __ATOMIC_RELAXED, __HIP_MEMORY_SCOPE_AGENT);
}
union F2U { u64 q; float2 f; };
__device__ __forceinline__ float2 ald_f2(const float* p) { F2U u; u.q = ald8(p); return u.f; }
__device__ __forceinline__ void ast_f2(float* p, float x, float y) {
    F2U u; u.f.x = x; u.f.y = y; ast8(p, u.q);
}
__device__ __forceinline__ bf16x8 ald_bf8(const unsigned short* p) {
    union { u64 q[2]; bf16x8 v; } u;
    u.q[0] = ald8(p); u.q[1] = ald8(p + 4);
    return u.v;
}

// ---- tree barrier memory (each counter on its own 64B line) ---------------
struct alignas(64) PadU { unsigned v; unsigned pad[15]; };
struct Bars {
    PadU leaf[NBAR][16];
    PadU root[NBAR];
    PadU rel[NBAR][16];
    PadU ready;
};

struct Args {
    const int   *lin, *rin, *lch, *rch;
    const float *emb;
    const float *W_ioux, *b_ioux, *W_iouh, *b_iouh;
    const float *W_fx, *b_fx, *W_fh, *b_fh;
    const float *Wh, *bh, *Wp, *bp;
    unsigned short *WiouhT, *WfhT, *WxT, *Whb, *xcat, *hbf;
    float *cbuf, *ioub, *fpre, *out;
    Bars *bars;
};

// ---- one-shot tree grid barrier (idx used exactly once per call) ----------
__device__ __forceinline__ void grid_bar(Bars* b, int idx)
{
    __syncthreads();   // emits s_waitcnt vmcnt(0): all sc-flagged stores at L3
    if (threadIdx.x == 0) {
        const int g = blockIdx.x & 15;      // 16 groups x 16 blocks
        asm volatile("" ::: "memory");
        const unsigned lo = __hip_atomic_fetch_add(&b->leaf[idx][g].v, 1u,
                                __ATOMIC_RELAXED, __HIP_MEMORY_SCOPE_AGENT);
        if (lo == 15u) {                    // last of group
            const unsigned ro = __hip_atomic_fetch_add(&b->root[idx].v, 1u,
                                __ATOMIC_RELAXED, __HIP_MEMORY_SCOPE_AGENT);
            if (ro == 15u)                  // last overall -> release all
                for (int i = 0; i < 16; ++i) ast4u(&b->rel[idx][i].v, 1u);
        }
        while (ald4(&b->rel[idx][g].v) == 0u)
            __builtin_amdgcn_s_sleep(1);
        asm volatile("" ::: "memory");
    }
    __syncthreads();
}

// 32x32 fp32->bf16 transpose tile via LDS; packed 4B coherent stores
__device__ __forceinline__
void ttile(const float* __restrict__ src, int lds_, unsigned short* __restrict__ dst,
           int ldd, int k0, int n0, float (*ts)[33], int tid)
{
    const int tx = tid & 31, ty = tid >> 5;
#pragma unroll
    for (int i = 0; i < 4; ++i)
        ts[ty + 8 * i][tx] = src[(size_t)(k0 + ty + 8 * i) * lds_ + n0 + tx];
    __syncthreads();
    const int tx2 = tid & 15, ty2 = tid >> 4;   // 2 k-positions per thread
#pragma unroll
    for (int i = 0; i < 2; ++i) {
        const int row = n0 + ty2 + 16 * i;
        const unsigned lo = f2bf(ts[2 * tx2][ty2 + 16 * i]);
        const unsigned hi = f2bf(ts[2 * tx2 + 1][ty2 + 16 * i]);
        ast4u(&dst[(size_t)row * ldd + k0 + 2 * tx2], lo | (hi << 16));
    }
}

// -------- prege: one 32row x 256col tile of xcat = bf16(emb[tok])@WxT^T ----
__device__ __forceinline__
void prege_task(int t, const Args& a, int tid)
{
    const int mt = t & 31, nb = t >> 5;
    const int w = tid >> 6, lane = tid & 63;
    const int m = lane & 15, q = lane >> 4;
    const int colbase = nb * 256 + w * 64;
    const int r0 = mt * 32 + m, r1 = r0 + 16;
    const int tok0 = (r0 < 512) ? a.lin[r0] : a.rin[r0 - 512];
    const int tok1 = (r1 < 512) ? a.lin[r1] : a.rin[r1 - 512];
    const float* A0 = a.emb + (size_t)tok0 * 512;
    const float* A1 = a.emb + (size_t)tok1 * 512;

    f32x4 acc[2][4];
#pragma unroll
    for (int i = 0; i < 2; ++i)
#pragma unroll
        for (int j = 0; j < 4; ++j) acc[i][j] = (f32x4){0.f, 0.f, 0.f, 0.f};

#pragma unroll 2
    for (int k0 = 0; k0 < 512; k0 += 32) {
        const int koff = k0 + q * 8;
        bf16x8 a0 = load_f32_as_bf8(A0 + koff);
        bf16x8 a1 = load_f32_as_bf8(A1 + koff);
#pragma unroll
        for (int jj = 0; jj < 4; ++jj) {
            bf16x8 b = *(const bf16x8*)(a.WxT + (size_t)(colbase + jj * 16 + m) * 512 + koff);
            acc[0][jj] = mfma16(a0, b, acc[0][jj]);
            acc[1][jj] = mfma16(a1, b, acc[1][jj]);
        }
    }
#pragma unroll
    for (int i = 0; i < 2; ++i)
#pragma unroll
        for (int jj = 0; jj < 4; ++jj)
#pragma unroll
            for (int rr = 0; rr < 4; ++rr) {
                const int R = mt * 32 + i * 16 + q * 4 + rr;
                const int col = colbase + jj * 16 + m;
                const float bias = (col < 1536) ? a.b_ioux[col] : a.b_fx[col - 1536];
                const unsigned me = f2bf(acc[i][jj][rr] + bias);
                const unsigned ov = __shfl_xor((int)me, 1, 64);
                if (!(m & 1))
                    ast4u(&a.xcat[(size_t)R * 2048 + col], me | (ov << 16));
            }
}

// -------- per-phase fused gather + dual GEMM (one task, per-wave slice) ----
__device__ __forceinline__
void gemm_task(int t, int lo, int B, int mti1, int nti1, int mti2,
               const Args& a, int w, int lane)
{
    const int B2 = 2 * B;
    const int m = lane & 15, q = lane >> 4;

    if (t < nti1) {
        // iou: [B2,512] (child-h sum, gathered on the fly) x [512,1536]
        const int mt = t % mti1, nb = t / mti1;
        const int colbase = nb * 256 + w * 64;
        const unsigned short* pA[2][4];
#pragma unroll
        for (int i = 0; i < 2; ++i) {
            const int r = mt * 32 + m + i * 16;
            int c[4] = {512, 512, 512, 512};
            int tree = 0;
            if (r < B2) {
                tree = (r >= B) ? 1 : 0;
                const int j = lo + r - tree * B;
                const int* ch = (tree ? a.rch : a.lch) + 4 * j;
                c[0] = ch[0]; c[1] = ch[1]; c[2] = ch[2]; c[3] = ch[3];
            }
            const unsigned short* hb = a.hbf + (size_t)tree * 513 * 512;
#pragma unroll
            for (int s = 0; s < 4; ++s) pA[i][s] = hb + (size_t)c[s] * 512;
        }
        f32x4 acc[2][4];
#pragma unroll
        for (int i = 0; i < 2; ++i)
#pragma unroll
            for (int j = 0; j < 4; ++j) acc[i][j] = (f32x4){0.f, 0.f, 0.f, 0.f};

#pragma unroll 2
        for (int k0 = 0; k0 < 512; k0 += 32) {
            const int koff = k0 + q * 8;
            bf16x8 af[2];
#pragma unroll
            for (int i = 0; i < 2; ++i) {
                float s[8] = {0.f, 0.f, 0.f, 0.f, 0.f, 0.f, 0.f, 0.f};
#pragma unroll
                for (int cc = 0; cc < 4; ++cc) {
                    bf16x8 v = ald_bf8(pA[i][cc] + koff);
#pragma unroll
                    for (int j = 0; j < 8; ++j) s[j] += (float)v[j];
                }
                bf16x8 av;
#pragma unroll
                for (int j = 0; j < 8; ++j) av[j] = (__bf16)s[j];
                af[i] = av;
            }
#pragma unroll
            for (int jj = 0; jj < 4; ++jj) {
                bf16x8 b = *(const bf16x8*)(a.WiouhT + (size_t)(colbase + jj * 16 + m) * 512 + koff);
                acc[0][jj] = mfma16(af[0], b, acc[0][jj]);
                acc[1][jj] = mfma16(af[1], b, acc[1][jj]);
            }
        }
#pragma unroll
        for (int i = 0; i < 2; ++i)
#pragma unroll
            for (int jj = 0; jj < 4; ++jj)
#pragma unroll
                for (int rr = 0; rr < 4; ++rr) {
                    const int R = mt * 32 + i * 16 + q * 4 + rr;
                    const int col = colbase + jj * 16 + m;
                    const int tr = (R >= B) ? 1 : 0;
                    const int jR = lo + R - tr * B;
                    float v = 0.f;
                    if (R < B2)
                        v = acc[i][jj][rr] + a.b_iouh[col]
                          + bf2f(a.xcat[(size_t)(tr * 512 + jR) * 2048 + col]);
                    const unsigned ov = __shfl_xor(__float_as_uint(v), 1, 64);
                    if (R < B2 && !(m & 1))
                        ast_f2(&a.ioub[(size_t)R * 1536 + col], v, __uint_as_float(ov));
                }
    } else {
        // f: [4*B2,512] (child h rows, direct) x [512,512]
        t -= nti1;
        const int mt = t % mti2, nb = t / mti2;
        const int colbase = nb * 256 + w * 64;
        const unsigned short* pA[2];
#pragma unroll
        for (int i = 0; i < 2; ++i) {
            const int rf = mt * 32 + m + i * 16;
            int tree = 0, c = 512;
            if (rf < 4 * B2) {
                const int r = rf >> 2, s = rf & 3;
                tree = (r >= B) ? 1 : 0;
                const int j = lo + r - tree * B;
                c = ((tree ? a.rch : a.lch) + 4 * j)[s];
            }
            pA[i] = a.hbf + ((size_t)tree * 513 + c) * 512;
        }
        f32x4 acc[2][4];
#pragma unroll
        for (int i = 0; i < 2; ++i)
#pragma unroll
            for (int j = 0; j < 4; ++j) acc[i][j] = (f32x4){0.f, 0.f, 0.f, 0.f};

#pragma unroll 2
        for (int k0 = 0; k0 < 512; k0 += 32) {
            const int koff = k0 + q * 8;
            bf16x8 a0 = ald_bf8(pA[0] + koff);
            bf16x8 a1 = ald_bf8(pA[1] + koff);
#pragma unroll
            for (int jj = 0; jj < 4; ++jj) {
                bf16x8 b = *(const bf16x8*)(a.WfhT + (size_t)(colbase + jj * 16 + m) * 512 + koff);
                acc[0][jj] = mfma16(a0, b, acc[0][jj]);
                acc[1][jj] = mfma16(a1, b, acc[1][jj]);
            }
        }
#pragma unroll
        for (int i = 0; i < 2; ++i)
#pragma unroll
            for (int jj = 0; jj < 4; ++jj)
#pragma unroll
                for (int rr = 0; rr < 4; ++rr) {
                    const int R = mt * 32 + i * 16 + q * 4 + rr;
                    const int col = colbase + jj * 16 + m;
                    const int rR = R >> 2;
                    const int tr = (rR >= B) ? 1 : 0;
                    const int jR = lo + rR - tr * B;
                    float v = 0.f;
                    if (R < 4 * B2)
                        v = acc[i][jj][rr] + a.b_fh[col]
                          + bf2f(a.xcat[(size_t)(tr * 512 + jR) * 2048 + 1536 + col]);
                    const unsigned ov = __shfl_xor(__float_as_uint(v), 1, 64);
                    if (R < 4 * B2 && !(m & 1))
                        ast_f2(&a.fpre[(size_t)R * 512 + col], v, __uint_as_float(ov));
                }
    }
}

// -------- general gating, 2 cols/thread (writes c fp32 8B, h bf16 4B) ------
__device__ __forceinline__
void gate_row(int r, int lo, int B, const Args& a)
{
    const int t2 = threadIdx.x * 2;
    const int tree = (r >= B) ? 1 : 0;
    const int j = lo + r - tree * B;
    const int* ch = (tree ? a.rch : a.lch) + 4 * j;
    const int c0 = ch[0], c1 = ch[1], c2 = ch[2], c3 = ch[3];
    float* cb = a.cbuf + (size_t)tree * 513 * 512;
    unsigned short* hb = a.hbf + (size_t)tree * 513 * 512;
    const float* ir = a.ioub + (size_t)r * 1536;
    const float* fr = a.fpre + (size_t)r * 4 * 512;

    const float2 igv = ald_f2(ir + t2);
    const float2 ogv = ald_f2(ir + 512 + t2);
    const float2 ugv = ald_f2(ir + 1024 + t2);
    const float2 f0 = ald_f2(fr + t2);
    const float2 f1 = ald_f2(fr + 512 + t2);
    const float2 f2v = ald_f2(fr + 1024 + t2);
    const float2 f3 = ald_f2(fr + 1536 + t2);
    const float2 cc0 = ald_f2(cb + (size_t)c0 * 512 + t2);
    const float2 cc1 = ald_f2(cb + (size_t)c1 * 512 + t2);
    const float2 cc2 = ald_f2(cb + (size_t)c2 * 512 + t2);
    const float2 cc3 = ald_f2(cb + (size_t)c3 * 512 + t2);

    const float cvx = sigm(igv.x) * tanhf(ugv.x)
        + sigm(f0.x) * cc0.x + sigm(f1.x) * cc1.x
        + sigm(f2v.x) * cc2.x + sigm(f3.x) * cc3.x;
    const float cvy = sigm(igv.y) * tanhf(ugv.y)
        + sigm(f0.y) * cc0.y + sigm(f1.y) * cc1.y
        + sigm(f2v.y) * cc2.y + sigm(f3.y) * cc3.y;
    ast_f2(cb + (size_t)j * 512 + t2, cvx, cvy);
    const unsigned hp = (unsigned)f2bf(sigm(ogv.x) * tanhf(cvx))
                      | ((unsigned)f2bf(sigm(ogv.y) * tanhf(cvy)) << 16);
    ast4u(hb + (size_t)j * 512 + t2, hp);
}

// ---------------------------- the mega-kernel ------------------------------
__global__ __launch_bounds__(256, 1)
void mega(Args a)
{
    const int tid = threadIdx.x, bid = blockIdx.x;
    const int G = gridDim.x;
    __shared__ float ts[32][33];

    // ---- barrier init: ws is poisoned 0xAA each call ----
    if (bid == 0) {
        unsigned* z = (unsigned*)a.bars;
        const int nz = (int)(offsetof(Bars, ready) / 4);   // zero all but ready
        for (int i = tid; i < nz; i += 256) ast4u(&z[i], 0u);
        __syncthreads();                                   // drains vmcnt(0)
        if (tid == 0) ast4u(&a.bars->ready.v, READY_MAGIC);
    }
    if (tid == 0) {
        while (ald4(&a.bars->ready.v) != READY_MAGIC)
            __builtin_amdgcn_s_sleep(1);
        asm volatile("" ::: "memory");
    }
    __syncthreads();
    int bi = 0;   // barrier index (uniform across blocks)

    // ---- S1: WxT transpose (prege's weights) + zero pad rows (1025 tasks) --
    for (int t = bid; t < 1025; t += G) {
        if (t < 768) {                       // W_ioux [512][1536] -> WxT[0,1536)
            ttile(a.W_ioux, 1536, a.WxT, 512, (t & 15) * 32, (t >> 4) * 32, ts, tid);
        } else if (t < 1024) {               // W_fx -> WxT rows [1536,2048)
            const int tt = t - 768;
            ttile(a.W_fx, 512, a.WxT + (size_t)1536 * 512, 512, (tt & 15) * 32, (tt >> 4) * 32, ts, tid);
        } else {                             // zero pad rows (child idx 512)
            u64* h0 = (u64*)(a.hbf + (size_t)512 * 512);
            u64* h1 = (u64*)(a.hbf + (size_t)1025 * 512);
            for (int i = tid; i < 128; i += 256) { ast8(&h0[i], 0ull); ast8(&h1[i], 0ull); }
            u64* c0p = (u64*)(a.cbuf + (size_t)512 * 512);
            u64* c1p = (u64*)(a.cbuf + (size_t)1025 * 512);
            for (int i = tid; i < 256; i += 256) { ast8(&c0p[i], 0ull); ast8(&c1p[i], 0ull); }
        }
        __syncthreads();                     // ts reusable next iteration
    }
    grid_bar(a.bars, bi++);

    // ---- S2: prege (256) OVERLAPPED with WiouhT/WfhT/Whb prep (1280) -------
    for (int t = bid; t < 1536; t += G) {
        if (t < 256) {                       // xcat tile GEMM
            prege_task(t, a, tid);
        } else if (t < 1024) {               // W_iouh [512][1536] -> WiouhT
            const int tt = t - 256;
            ttile(a.W_iouh, 1536, a.WiouhT, 512, (tt & 15) * 32, (tt >> 4) * 32, ts, tid);
        } else if (t < 1280) {               // W_fh -> WfhT
            const int tt = t - 1024;
            ttile(a.W_fh, 512, a.WfhT, 512, (tt & 15) * 32, (tt >> 4) * 32, ts, tid);
        } else {                             // Wh -> bf16 copy (4B packed)
            unsigned* dst = (unsigned*)a.Whb;
            const size_t base = (size_t)(t - 1280) * 1024 + tid;
#pragma unroll
            for (int i = 0; i < 4; ++i) {
                const size_t idx = base + 256 * i;
                const unsigned lo = f2bf(a.Wh[2 * idx]);
                const unsigned hi = f2bf(a.Wh[2 * idx + 1]);
                ast4u(&dst[idx], lo | (hi << 16));
            }
        }
        __syncthreads();
    }
    grid_bar(a.bars, bi++);

    // ---- S3: leaf gating (children all pad-zero; GEMM acc == 0) ----
    {
        const int t2 = tid * 2;
        const float2 bi0 = *(const float2*)(a.b_iouh + t2);
        const float2 bi1 = *(const float2*)(a.b_iouh + 512 + t2);
        const float2 bi2 = *(const float2*)(a.b_iouh + 1024 + t2);
        for (int r = bid; r < 342; r += G) {
            const int tree = (r >= 171) ? 1 : 0;
            const int j = r - tree * 171;
            const unsigned short* xr = a.xcat + (size_t)(tree * 512 + j) * 2048;
            float* cb = a.cbuf + (size_t)tree * 513 * 512;
            unsigned short* hb = a.hbf + (size_t)tree * 513 * 512;
            const unsigned x0 = *(const unsigned*)(xr + t2);
            const unsigned x1 = *(const unsigned*)(xr + 512 + t2);
            const unsigned x2 = *(const unsigned*)(xr + 1024 + t2);
            const float cvx = sigm(bf2f((unsigned short)x0) + bi0.x)
                            * tanhf(bf2f((unsigned short)x2) + bi2.x);
            const float cvy = sigm(bf2f((unsigned short)(x0 >> 16)) + bi0.y)
                            * tanhf(bf2f((unsigned short)(x2 >> 16)) + bi2.y);
            const float ogx = sigm(bf2f((unsigned short)x1) + bi1.x);
            const float ogy = sigm(bf2f((unsigned short)(x1 >> 16)) + bi1.y);
            ast_f2(cb + (size_t)j * 512 + t2, cvx, cvy);
            const unsigned hp = (unsigned)f2bf(ogx * tanhf(cvx))
                              | ((unsigned)f2bf(ogy * tanhf(cvy)) << 16);
            ast4u(hb + (size_t)j * 512 + t2, hp);
        }
    }
    grid_bar(a.bars, bi++);

    // ---- phases d4..d1: fused gather+GEMM -> bar -> gating -> bar ----
    static const int los[4] = {171, 427, 491, 507};
    static const int Bs[4]  = {256, 64, 16, 4};
    for (int ph = 0; ph < 4; ++ph) {
        const int lo = los[ph], B = Bs[ph], B2 = 2 * B;
        const int mti1 = (B2 + 31) >> 5, mti2 = (4 * B2 + 31) >> 5;
        const int nti1 = mti1 * 6;
        const int ntot = nti1 + mti2 * 2;
        for (int t = bid; t < ntot; t += G)
            gemm_task(t, lo, B, mti1, nti1, mti2, a, tid >> 6, tid & 63);
        grid_bar(a.bars, bi++);
        for (int r = bid; r < B2; r += G)
            gate_row(r, lo, B, a);
        grid_bar(a.bars, bi++);
    }

    // ---- finale (block 0): root GEMM (wave-sliced) + gating + head --------
    if (bid == 0) {
        const int wv = tid >> 6, lane = tid & 63;
        // root gemm: lo=511, B=1 -> 8 tasks, each wave does its 64-col slice
        for (int t = 0; t < 8; ++t)
            gemm_task(t, 511, 1, 1, 6, 1, a, wv, lane);
        __syncthreads();   // own coherent stores drained -> readable below

        __shared__ float sv[1024];
        const int t2 = tid * 2;
        // root cell states (og/h not needed: head consumes CELL states)
#pragma unroll
        for (int tree = 0; tree < 2; ++tree) {
            const int* ch = (tree ? a.rch : a.lch) + 4 * 511;
            const float* cb = a.cbuf + (size_t)tree * 513 * 512;
            const float* ir = a.ioub + (size_t)tree * 1536;
            const float* fr = a.fpre + (size_t)tree * 4 * 512;
            const float2 igv = ald_f2(ir + t2);
            const float2 ugv = ald_f2(ir + 1024 + t2);
            const float2 f0 = ald_f2(fr + t2);
            const float2 f1 = ald_f2(fr + 512 + t2);
            const float2 f2v = ald_f2(fr + 1024 + t2);
            const float2 f3 = ald_f2(fr + 1536 + t2);
            const float2 cc0 = ald_f2(cb + (size_t)ch[0] * 512 + t2);
            const float2 cc1 = ald_f2(cb + (size_t)ch[1] * 512 + t2);
            const float2 cc2 = ald_f2(cb + (size_t)ch[2] * 512 + t2);
            const float2 cc3 = ald_f2(cb + (size_t)ch[3] * 512 + t2);
            sv[tree * 512 + t2] = sigm(igv.x) * tanhf(ugv.x)
                + sigm(f0.x) * cc0.x + sigm(f1.x) * cc1.x
                + sigm(f2v.x) * cc2.x + sigm(f3.x) * cc3.x;
            sv[tree * 512 + t2 + 1] = sigm(igv.y) * tanhf(ugv.y)
                + sigm(f0.y) * cc0.y + sigm(f1.y) * cc1.y
                + sigm(f2v.y) * cc2.y + sigm(f3.y) * cc3.y;
        }
        __syncthreads();
        // vec = [lc*rc, |lc-rc|] in place
#pragma unroll
        for (int u = 0; u < 2; ++u) {
            const int k = tid + u * 256;
            if (k < 512) {
                const float lcv = sv[k], rcv = sv[512 + k];
                sv[k] = lcv * rcv;
                sv[512 + k] = fabsf(lcv - rcv);
            }
        }
        __syncthreads();
        // hid = sigmoid(vec @ Wh + bh); each thread owns cols 2t, 2t+1
        float a0 = 0.f, a1 = 0.f;
#pragma unroll 4
        for (int k = 0; k < 1024; ++k) {
            const unsigned int wvv = *(const unsigned int*)(a.Whb + (size_t)k * 512 + t2);
            const float s = sv[k];
            a0 += s * bf2f((unsigned short)(wvv & 0xffffu));
            a1 += s * bf2f((unsigned short)(wvv >> 16));
        }
        const float h0 = sigm(a0 + a.bh[t2]);
        const float h1 = sigm(a1 + a.bh[t2 + 1]);
        float lp[5];
#pragma unroll
        for (int cc = 0; cc < 5; ++cc)
            lp[cc] = h0 * a.Wp[(size_t)t2 * 5 + cc]
                   + h1 * a.Wp[(size_t)(t2 + 1) * 5 + cc];
#pragma unroll
        for (int cc = 0; cc < 5; ++cc)
#pragma unroll
            for (int off = 32; off; off >>= 1)
                lp[cc] += __shfl_xor(lp[cc], off, 64);
        __shared__ float red[4][5];
        const int w = tid >> 6;
        if (lane == 0)
#pragma unroll
            for (int cc = 0; cc < 5; ++cc) red[w][cc] = lp[cc];
        __syncthreads();
        if (tid == 0) {
            float lg[5], mx = -1e30f;
#pragma unroll
            for (int cc = 0; cc < 5; ++cc) {
                lg[cc] = red[0][cc] + red[1][cc] + red[2][cc] + red[3][cc] + a.bp[cc];
                mx = fmaxf(mx, lg[cc]);
            }
            float s = 0.f;
#pragma unroll
            for (int cc = 0; cc < 5; ++cc) s += __expf(lg[cc] - mx);
            const float lse = mx + __logf(s);
#pragma unroll
            for (int cc = 0; cc < 5; ++cc) a.out[cc] = lg[cc] - lse;
        }
    }
}

// ---------------- launch ----------------------------------------------------
extern "C" void kernel_launch(void* const* d_in, const int* in_sizes, int n_in,
                              void* d_out, int out_size, void* d_ws, size_t ws_size,
                              hipStream_t stream)
{
    (void)ws_size; (void)n_in; (void)in_sizes; (void)out_size;

    Args ha;
    ha.lin     = (const int*)d_in[0];
    ha.rin     = (const int*)d_in[1];
    ha.lch     = (const int*)d_in[2];
    ha.rch     = (const int*)d_in[3];
    ha.emb     = (const float*)d_in[4];
    ha.W_ioux  = (const float*)d_in[5];
    ha.b_ioux  = (const float*)d_in[6];
    ha.W_iouh  = (const float*)d_in[7];
    ha.b_iouh  = (const float*)d_in[8];
    ha.W_fx    = (const float*)d_in[9];
    ha.b_fx    = (const float*)d_in[10];
    ha.W_fh    = (const float*)d_in[11];
    ha.b_fh    = (const float*)d_in[12];
    ha.Wh      = (const float*)d_in[13];
    ha.bh      = (const float*)d_in[14];
    ha.Wp      = (const float*)d_in[15];
    ha.bp      = (const float*)d_in[16];
    ha.out     = (float*)d_out;

    char* p = (char*)d_ws;
    ha.WiouhT = (unsigned short*)p;  p += (size_t)1536 * 512 * 2;
    ha.WfhT   = (unsigned short*)p;  p += (size_t)512 * 512 * 2;
    ha.WxT    = (unsigned short*)p;  p += (size_t)2048 * 512 * 2;
    ha.Whb    = (unsigned short*)p;  p += (size_t)1024 * 512 * 2;
    ha.xcat   = (unsigned short*)p;  p += (size_t)1024 * 2048 * 2;
    ha.hbf    = (unsigned short*)p;  p += (size_t)2 * 513 * 512 * 2;
    ha.cbuf   = (float*)p;           p += (size_t)2 * 513 * 512 * 4;
    ha.ioub   = (float*)p;           p += (size_t)512 * 1536 * 4;
    ha.fpre   = (float*)p;           p += (size_t)2048 * 512 * 4;
    ha.bars   = (Bars*)p;            p += sizeof(Bars);

    void* kargs[] = { &ha };
    hipLaunchCooperativeKernel((const void*)mega, dim3(GRID), dim3(256),
                               kargs, 0, stream);
}